// Round 16
// baseline (63.584 us; speedup 1.0000x reference)
//
#include <hip/hip_runtime.h>

// ---------------------------------------------------------------------------
// AttentionHead: GroupNorm -> QKV 1x1 conv -> softmax attention -> 1x1 conv.
// Round 16: attn LDS-pipe attack. 64 q-rows/wave: two q-subtiles share every
// K/V ds_read_b128 (halves per-CU LDS-read cycles, the dominant pipe at
// ~10us). Unlike r8 (null), staging is global_load_lds (no staging VGPRs,
// no VMEM round-trip) and exp2 is single-instruction. 2 blocks/CU
// (launch_bounds(256,2)), grid 512, serial m-groups to cap live registers.
// gn_stats / gn_qkv / out_proj byte-identical to r15 (63.5us verified).
// ---------------------------------------------------------------------------

#define B_ 4
#define C_ 64
#define D_ 64
#define N_ 4096

using bf16x8 = __attribute__((ext_vector_type(8))) short;     // 8 bf16 = 4 VGPR
using u16x8  = __attribute__((ext_vector_type(8))) unsigned short;
using u32x4  = __attribute__((ext_vector_type(4))) unsigned int;
using f32x16 = __attribute__((ext_vector_type(16))) float;
using h16x8  = __attribute__((ext_vector_type(8))) _Float16;

// round-to-nearest-even f32 -> bf16 bits
__device__ __forceinline__ unsigned short f2bf(float f) {
    unsigned u = __builtin_bit_cast(unsigned, f);
    u = (u + 0x7FFFu + ((u >> 16) & 1u)) >> 16;
    return (unsigned short)u;
}

// single-instruction exp2: builtin (backend-hazard-managed) or asm + s_nop
#if __has_builtin(__builtin_amdgcn_exp2f)
__device__ __forceinline__ float fast_exp2(float x) {
    return __builtin_amdgcn_exp2f(x);
}
#else
__device__ __forceinline__ float fast_exp2(float x) {
    float r;
    asm volatile("v_exp_f32 %0, %1\n\ts_nop 1" : "=v"(r) : "v"(x));
    return r;
}
#endif

// async global->LDS, 16B per lane (lds dst wave-uniform base, +lane*16)
__device__ __forceinline__ void gload16(const void* g, void* l) {
    __builtin_amdgcn_global_load_lds(
        (const __attribute__((address_space(1))) unsigned int*)g,
        (__attribute__((address_space(3))) unsigned int*)l, 16, 0, 0);
}

// ---------------------------------------------------------------------------
// Kernel 1: per-(b,c) mean / rsqrt(var+eps) over H*W = 4096
// ---------------------------------------------------------------------------
__global__ __launch_bounds__(1024)
void gn_stats_kernel(const float* __restrict__ x, float* __restrict__ stats) {
    __shared__ float red[32];
    const int bx  = blockIdx.x;
    const int tid = threadIdx.x;
    const float4* xp = (const float4*)(x + (size_t)bx * N_);
    float4 v = xp[tid];
    float s = (v.x + v.y) + (v.z + v.w);
    float q = (v.x * v.x + v.y * v.y) + (v.z * v.z + v.w * v.w);
#pragma unroll
    for (int off = 1; off < 64; off <<= 1) {
        s += __shfl_xor(s, off);
        q += __shfl_xor(q, off);
    }
    const int w = tid >> 6;
    if ((tid & 63) == 0) { red[w * 2] = s; red[w * 2 + 1] = q; }
    __syncthreads();
    if (w == 0) {
        const int lane = tid & 63;
        float sl = (lane < 16) ? red[lane * 2] : 0.f;
        float ql = (lane < 16) ? red[lane * 2 + 1] : 0.f;
#pragma unroll
        for (int off = 1; off < 16; off <<= 1) {
            sl += __shfl_xor(sl, off);
            ql += __shfl_xor(ql, off);
        }
        if (lane == 0) {
            float mu  = sl * (1.f / 4096.f);
            float var = ql * (1.f / 4096.f) - mu * mu;
            var = fmaxf(var, 0.f);
            stats[bx * 2]     = mu;
            stats[bx * 2 + 1] = 1.f / sqrtf(var + 1e-5f);
        }
    }
}

// ---------------------------------------------------------------------------
// Kernel 2: GroupNorm apply + QKV projections -> MFMA-frag layouts (r7).
// ---------------------------------------------------------------------------
__global__ __launch_bounds__(512)
void gn_qkv_kernel(const float* __restrict__ x, const float* __restrict__ stats,
                   const float* __restrict__ gnw, const float* __restrict__ gnb,
                   const float* __restrict__ wq, const float* __restrict__ bq,
                   const float* __restrict__ wk, const float* __restrict__ bk,
                   const float* __restrict__ wv, const float* __restrict__ bv,
                   unsigned short* __restrict__ Qt, unsigned short* __restrict__ Kf,
                   unsigned short* __restrict__ Vf) {
    __shared__ float xn[64 * 64];                 // [c][n] 16 KB
    __shared__ __align__(16) char vs[64 * 128];   // [m][d] bf16, XOR-swizzled, 8 KB
    const int t  = threadIdx.x;
    const int bx = blockIdx.x;
    const int b  = bx >> 6;
    const int n0 = (bx & 63) * 64;

    // ---- Phase A: load + normalize x tile ----
    {
        const int c  = t >> 3;
        const int nc = (t & 7) * 8;
        const float* xp = x + (size_t)(b * 64 + c) * N_ + n0 + nc;
        float4 xa = *(const float4*)(xp);
        float4 xb = *(const float4*)(xp + 4);
        float mu = stats[(b * 64 + c) * 2];
        float rs = stats[(b * 64 + c) * 2 + 1];
        float gw = gnw[c] * rs;
        float gb = gnb[c] - mu * gw;
        float* xr = xn + c * 64 + nc;
        xr[0] = xa.x * gw + gb; xr[1] = xa.y * gw + gb;
        xr[2] = xa.z * gw + gb; xr[3] = xa.w * gw + gb;
        xr[4] = xb.x * gw + gb; xr[5] = xb.y * gw + gb;
        xr[6] = xb.z * gw + gb; xr[7] = xb.w * gw + gb;
    }
    __syncthreads();

    // ---- Phase B: per (n, 8d) dot products ----
    const int n    = t & 63;
    const int dblk = __builtin_amdgcn_readfirstlane(t >> 6);
    const int d0   = dblk * 8;

    float aq[8], ak[8], av[8];
#pragma unroll
    for (int i = 0; i < 8; ++i) { aq[i] = 0.f; ak[i] = 0.f; av[i] = 0.f; }

#pragma unroll 4
    for (int c = 0; c < 64; ++c) {
        const float xv = xn[c * 64 + n];
#pragma unroll
        for (int i = 0; i < 8; ++i) {
            aq[i] += wq[(d0 + i) * 64 + c] * xv;
            ak[i] += wk[(d0 + i) * 64 + c] * xv;
            av[i] += wv[(d0 + i) * 64 + c] * xv;
        }
    }

    const float QS = 0.18033688011112042f;  // 0.125 * log2(e): exp2-domain logits
    const int m = n0 + n;
    u16x8 qv, kv, vb;
#pragma unroll
    for (int i = 0; i < 8; ++i) {
        qv[i] = f2bf((aq[i] + bq[d0 + i]) * QS);
        kv[i] = f2bf(ak[i] + bk[d0 + i]);
        vb[i] = f2bf(av[i] + bv[d0 + i]);
    }
    // Q: [n][d] row store (16B)
    *(u16x8*)(Qt + ((size_t)(b * N_ + m)) * 64 + d0) = qv;
    // K: direct frag store
    {
        const int kc = dblk >> 1, h = dblk & 1, mt = m >> 5;
        *(u16x8*)(Kf + ((size_t)((b * 128 + mt) * 4 + kc)) * 512
                     + (h * 32 + (m & 31)) * 8) = kv;
    }
    // V: swizzled LDS stage
    *(u16x8*)(vs + n * 128 + ((dblk * 16) ^ ((n & 7) << 4))) = vb;
    __syncthreads();

    // ---- Phase C: frag-ordered Vf copyout (one 16B store per thread) ----
    {
        const int mc_l = t >> 7;            // 0..3
        const int dt   = (t >> 6) & 1;
        const int lp   = t & 63;
        const int hp   = lp >> 5;
        const int dcol = (lp & 31) + dt * 32;
        const int cbase = (dcol & ~7) * 2;
        const int clow  = (dcol & 7) * 2;
        u16x8 tmp;
#pragma unroll
        for (int j = 0; j < 8; ++j) {
            const int ml = mc_l * 16 + hp * 8 + j;   // ml&7 == j
            tmp[j] = *(const unsigned short*)(
                vs + ml * 128 + (cbase ^ (j << 4)) + clow);
        }
        *(u16x8*)(Vf + ((size_t)((b * 256 + (n0 >> 4) + mc_l) * 2 + dt)) * 512
                     + lp * 8) = tmp;
    }
}

// ---------------------------------------------------------------------------
// Kernel 3: attention, LDS-staged via global_load_lds, 64 q-rows/wave.
// grid = 512 blocks (b = bid&3, qb = (bid>>2)&15, s = bid>>6), 256 thr,
// 2 blocks/CU. Wave wvu: q-rows [qb*256 + wvu*64, +64) as two 32-row
// subtiles sharing every K/V fragment ds_read (halves LDS-pipe traffic).
// Per 64-m tile: stage t+1 via gload_lds; per m-group g (serial):
// 4 ds_read K -> 2 interleaved 4-MFMA S-chains; exp2 x32 (4 sum chains);
// 2x pack; 4 ds_read V -> 8 MFMA O (4 acc chains); barrier per tile.
// ---------------------------------------------------------------------------
__global__ __launch_bounds__(256, 2)
void attn_kernel(const unsigned short* __restrict__ Qt,
                 const unsigned short* __restrict__ Kf,
                 const unsigned short* __restrict__ Vf,
                 _Float16* __restrict__ Opart, float* __restrict__ Lpart,
                 int mspan) {
    __shared__ __align__(16) char smem[2 * 16384];
    const int tid  = threadIdx.x;
    const int lane = tid & 63;
    const int wvu  = __builtin_amdgcn_readfirstlane(tid >> 6);   // wave id 0..3
    const int c    = lane & 31;
    const int h    = lane >> 5;
    const int bid  = blockIdx.x;
    const int b    = bid & 3;
    const int t2   = bid >> 2;
    const int qb   = t2 & 15;
    const int s    = t2 >> 4;
    const int qg0  = qb * 256 + wvu * 64;

    // Q B-frags for the two 32-row subtiles
    const unsigned short* qp = Qt + (size_t)(b * N_ + qg0 + c) * 64 + h * 8;
    bf16x8 qa0[4], qa1[4];
#pragma unroll
    for (int kc = 0; kc < 4; ++kc) {
        qa0[kc] = *(const bf16x8*)(qp + kc * 16);
        qa1[kc] = *(const bf16x8*)(qp + 32 * 64 + kc * 16);
    }

    f32x16 o00, o01, o10, o11;
#pragma unroll
    for (int i = 0; i < 16; ++i) { o00[i] = 0.f; o01[i] = 0.f; o10[i] = 0.f; o11[i] = 0.f; }
    float lsA0 = 0.f, lsA1 = 0.f, lsB0 = 0.f, lsB1 = 0.f;

    const int NT = mspan >> 6;
    const int mstart = s * mspan;
    const int lof = lane * 16;

    // running staging pointers (advance 8 KB per 64-m tile)
    const char* kTn = (const char*)Kf + (size_t)b * 524288
                      + (size_t)(mstart >> 5) * 4096;
    const char* vTn = (const char*)Vf + (size_t)b * 524288
                      + (size_t)(mstart >> 4) * 2048;

    // ---- prologue: async-stage tile 0 into buf0 ----
    gload16(kTn + (wvu    ) * 1024 + lof, smem + (wvu    ) * 1024);
    gload16(kTn + (wvu + 4) * 1024 + lof, smem + (wvu + 4) * 1024);
    gload16(vTn + (wvu    ) * 1024 + lof, smem + 8192 + (wvu    ) * 1024);
    gload16(vTn + (wvu + 4) * 1024 + lof, smem + 8192 + (wvu + 4) * 1024);
    __syncthreads();   // drains vmcnt -> tile 0 visible

    for (int t = 0; t < NT; ++t) {
        char* buf = smem + ((t & 1) ? 16384 : 0);
        // ---- issue next-tile async stage into the other buffer ----
        if (t + 1 < NT) {
            kTn += 8192;
            vTn += 8192;
            char* dst = smem + ((t & 1) ? 0 : 16384);
            gload16(kTn + (wvu    ) * 1024 + lof, dst + (wvu    ) * 1024);
            gload16(kTn + (wvu + 4) * 1024 + lof, dst + (wvu + 4) * 1024);
            gload16(vTn + (wvu    ) * 1024 + lof, dst + 8192 + (wvu    ) * 1024);
            gload16(vTn + (wvu + 4) * 1024 + lof, dst + 8192 + (wvu + 4) * 1024);
        }

        // ---- compute current tile: 2 m-groups, serial; subtiles interleaved
#pragma unroll
        for (int g = 0; g < 2; ++g) {
            const char* kb = buf + g * 4096 + lof;
            bf16x8 kf0 = *(const bf16x8*)(kb);
            bf16x8 kf1 = *(const bf16x8*)(kb + 1024);
            bf16x8 kf2 = *(const bf16x8*)(kb + 2048);
            bf16x8 kf3 = *(const bf16x8*)(kb + 3072);
            f32x16 sa0, sa1;
#pragma unroll
            for (int i = 0; i < 16; ++i) { sa0[i] = 0.f; sa1[i] = 0.f; }
            // two independent S-chains (subtile0, subtile1), alternating
            sa0 = __builtin_amdgcn_mfma_f32_32x32x16_bf16(kf0, qa0[0], sa0, 0, 0, 0);
            sa1 = __builtin_amdgcn_mfma_f32_32x32x16_bf16(kf0, qa1[0], sa1, 0, 0, 0);
            sa0 = __builtin_amdgcn_mfma_f32_32x32x16_bf16(kf1, qa0[1], sa0, 0, 0, 0);
            sa1 = __builtin_amdgcn_mfma_f32_32x32x16_bf16(kf1, qa1[1], sa1, 0, 0, 0);
            sa0 = __builtin_amdgcn_mfma_f32_32x32x16_bf16(kf2, qa0[2], sa0, 0, 0, 0);
            sa1 = __builtin_amdgcn_mfma_f32_32x32x16_bf16(kf2, qa1[2], sa1, 0, 0, 0);
            sa0 = __builtin_amdgcn_mfma_f32_32x32x16_bf16(kf3, qa0[3], sa0, 0, 0, 0);
            sa1 = __builtin_amdgcn_mfma_f32_32x32x16_bf16(kf3, qa1[3], sa1, 0, 0, 0);

            // P = exp2(S^T) both subtiles; 4 independent sum chains
#pragma unroll
            for (int i = 0; i < 16; i += 2) {
                float pA0 = fast_exp2(sa0[i]);
                float pA1 = fast_exp2(sa0[i + 1]);
                float pB0 = fast_exp2(sa1[i]);
                float pB1 = fast_exp2(sa1[i + 1]);
                sa0[i] = pA0; sa0[i + 1] = pA1;
                sa1[i] = pB0; sa1[i + 1] = pB1;
                lsA0 += pA0; lsA1 += pA1;
                lsB0 += pB0; lsB1 += pB1;
            }
            // pack both subtiles to bf16 pairs and swap halves
            unsigned dwa[8], dwb[8];
#pragma unroll
            for (int i = 0; i < 8; ++i) {
                asm("v_cvt_pk_bf16_f32 %0, %1, %2"
                    : "=v"(dwa[i]) : "v"(sa0[2 * i]), "v"(sa0[2 * i + 1]));
                asm("v_cvt_pk_bf16_f32 %0, %1, %2"
                    : "=v"(dwb[i]) : "v"(sa1[2 * i]), "v"(sa1[2 * i + 1]));
            }
            asm("v_permlane32_swap_b32 %0, %1" : "+v"(dwa[0]), "+v"(dwa[2]));
            asm("v_permlane32_swap_b32 %0, %1" : "+v"(dwa[1]), "+v"(dwa[3]));
            asm("v_permlane32_swap_b32 %0, %1" : "+v"(dwa[4]), "+v"(dwa[6]));
            asm("v_permlane32_swap_b32 %0, %1" : "+v"(dwa[5]), "+v"(dwa[7]));
            asm("v_permlane32_swap_b32 %0, %1" : "+v"(dwb[0]), "+v"(dwb[2]));
            asm("v_permlane32_swap_b32 %0, %1" : "+v"(dwb[1]), "+v"(dwb[3]));
            asm("v_permlane32_swap_b32 %0, %1" : "+v"(dwb[4]), "+v"(dwb[6]));
            asm("v_permlane32_swap_b32 %0, %1" : "+v"(dwb[5]), "+v"(dwb[7]));
            bf16x8 pa0 = __builtin_bit_cast(bf16x8, (u32x4){dwa[0], dwa[1], dwa[2], dwa[3]});
            bf16x8 pa1 = __builtin_bit_cast(bf16x8, (u32x4){dwa[4], dwa[5], dwa[6], dwa[7]});
            bf16x8 pb0 = __builtin_bit_cast(bf16x8, (u32x4){dwb[0], dwb[1], dwb[2], dwb[3]});
            bf16x8 pb1 = __builtin_bit_cast(bf16x8, (u32x4){dwb[4], dwb[5], dwb[6], dwb[7]});

            // PV both subtiles from the SAME V frag reads (4 acc chains)
            const char* vb = buf + 8192 + g * 4096 + lof;
            bf16x8 vf0 = *(const bf16x8*)(vb);
            bf16x8 vf1 = *(const bf16x8*)(vb + 1024);
            bf16x8 vf2 = *(const bf16x8*)(vb + 2048);
            bf16x8 vf3 = *(const bf16x8*)(vb + 3072);
            o00 = __builtin_amdgcn_mfma_f32_32x32x16_bf16(vf0, pa0, o00, 0, 0, 0);
            o10 = __builtin_amdgcn_mfma_f32_32x32x16_bf16(vf0, pb0, o10, 0, 0, 0);
            o01 = __builtin_amdgcn_mfma_f32_32x32x16_bf16(vf1, pa0, o01, 0, 0, 0);
            o11 = __builtin_amdgcn_mfma_f32_32x32x16_bf16(vf1, pb0, o11, 0, 0, 0);
            o00 = __builtin_amdgcn_mfma_f32_32x32x16_bf16(vf2, pa1, o00, 0, 0, 0);
            o10 = __builtin_amdgcn_mfma_f32_32x32x16_bf16(vf2, pb1, o10, 0, 0, 0);
            o01 = __builtin_amdgcn_mfma_f32_32x32x16_bf16(vf3, pa1, o01, 0, 0, 0);
            o11 = __builtin_amdgcn_mfma_f32_32x32x16_bf16(vf3, pb1, o11, 0, 0, 0);
        }

        // one barrier per tile: drains the async stage + publishes next buffer
        __syncthreads();
    }

    // rowsums (col q = own half + other half), per subtile
    float lsA = lsA0 + lsA1;
    float lsB = lsB0 + lsB1;
    float rsA = lsA + __shfl_xor(lsA, 32);
    float rsB = lsB + __shfl_xor(lsB, 32);

    const size_t s4b = (size_t)(s * 4 + b);
    _Float16* ob = Opart + (s4b * 64 << 12);
#pragma unroll
    for (int r = 0; r < 16; ++r) {
        const int row = (r & 3) + 8 * (r >> 2) + 4 * h;
        ob[((size_t)row << 12) + qg0 + c]             = (_Float16)o00[r];
        ob[((size_t)(row + 32) << 12) + qg0 + c]      = (_Float16)o01[r];
        ob[((size_t)row << 12) + qg0 + 32 + c]        = (_Float16)o10[r];
        ob[((size_t)(row + 32) << 12) + qg0 + 32 + c] = (_Float16)o11[r];
    }
    if (h == 0) {
        Lpart[(s4b << 12) + qg0 + c]      = rsA;
        Lpart[(s4b << 12) + qg0 + 32 + c] = rsB;
    }
}

// ---------------------------------------------------------------------------
// Kernel 4: merge fp16 partials, normalize, out = wo @ att + bo (r7).
// ---------------------------------------------------------------------------
__global__ __launch_bounds__(256)
void out_proj_kernel(const _Float16* __restrict__ Opart, const float* __restrict__ Lpart,
                     const float* __restrict__ wo, const float* __restrict__ bo,
                     float* __restrict__ out, int S) {
    __shared__ float invl[32];
    __shared__ float attm[64 * 33];   // [d][n], padded
    const int t  = threadIdx.x;
    const int bx = blockIdx.x;
    const int b  = bx >> 7;
    const int n0 = (bx & 127) * 32;

    if (t < 32) {
        float sum = 0.f;
        for (int s = 0; s < S; ++s)
            sum += Lpart[(((size_t)(s * 4 + b)) << 12) + n0 + t];
        invl[t] = 1.f / sum;
    }
    __syncthreads();

    {   // merge: thread (d = t>>2, 8 n at (t&3)*8); 16B fp16 loads
        const int d  = t >> 2;
        const int nb = (t & 3) * 8;
        float o[8] = {0.f, 0.f, 0.f, 0.f, 0.f, 0.f, 0.f, 0.f};
        for (int s = 0; s < S; ++s) {
            h16x8 v = *(const h16x8*)(
                Opart + (((size_t)((s * 4 + b) * 64 + d)) << 12) + n0 + nb);
#pragma unroll
            for (int j = 0; j < 8; ++j) o[j] += (float)v[j];
        }
#pragma unroll
        for (int j = 0; j < 8; ++j)
            attm[d * 33 + nb + j] = o[j] * invl[nb + j];
    }
    __syncthreads();

    const int nn = t & 31;
    const int e0 = (t >> 5) * 8;
    float acc[8];
#pragma unroll
    for (int i = 0; i < 8; ++i) acc[i] = bo[e0 + i];
#pragma unroll 8
    for (int d = 0; d < 64; ++d) {
        const float xv = attm[d * 33 + nn];
#pragma unroll
        for (int i = 0; i < 8; ++i) acc[i] += wo[(e0 + i) * 64 + d] * xv;
    }
#pragma unroll
    for (int i = 0; i < 8; ++i)
        out[((size_t)(b * 64 + e0 + i) << 12) + n0 + nn] = acc[i];
}

// ---------------------------------------------------------------------------
extern "C" void kernel_launch(void* const* d_in, const int* in_sizes, int n_in,
                              void* d_out, int out_size, void* d_ws, size_t ws_size,
                              hipStream_t stream) {
    const float* x   = (const float*)d_in[0];
    const float* gnw = (const float*)d_in[1];
    const float* gnb = (const float*)d_in[2];
    const float* wq  = (const float*)d_in[3];
    const float* bq  = (const float*)d_in[4];
    const float* wk  = (const float*)d_in[5];
    const float* bk  = (const float*)d_in[6];
    const float* wv  = (const float*)d_in[7];
    const float* bv  = (const float*)d_in[8];
    const float* wo  = (const float*)d_in[9];
    const float* bo  = (const float*)d_in[10];
    float* out = (float*)d_out;

    char* wsb = (char*)d_ws;
    float*          stats = (float*)wsb;                                  //   2 KB
    unsigned short* Qt    = (unsigned short*)(wsb + 2048);                //   2 MB
    unsigned short* Kf    = (unsigned short*)(wsb + 2048 + 2097152);      //   2 MB
    unsigned short* Vf    = (unsigned short*)(wsb + 2048 + 2 * 2097152);  //   2 MB

    const size_t base = 2048 + 3ull * 2097152;
    // per m-split slot: Lpart 4*4096*4 = 64 KB, Opart fp16 4*64*4096*2 = 2 MB
    auto need = [&](int S) {
        return base + (size_t)S * (65536 + 2097152);
    };
    const int S = (ws_size >= need(8)) ? 8
                : (ws_size >= need(4)) ? 4
                : (ws_size >= need(2)) ? 2 : 1;
    const int mspan = N_ / S;
    float*    Lpart = (float*)(wsb + base);
    _Float16* Opart = (_Float16*)(wsb + base + (size_t)S * 65536);

    gn_stats_kernel<<<dim3(B_ * C_), dim3(1024), 0, stream>>>(x, stats);
    gn_qkv_kernel<<<dim3(B_ * 64), dim3(512), 0, stream>>>(
        x, stats, gnw, gnb, wq, bq, wk, bk, wv, bv, Qt, Kf, Vf);
    attn_kernel<<<dim3(16 * 4 * S), dim3(256), 0, stream>>>(
        Qt, Kf, Vf, Opart, Lpart, mspan);
    out_proj_kernel<<<dim3(B_ * 128), dim3(256), 0, stream>>>(
        Opart, Lpart, wo, bo, out, S);
}

// Round 17
// 63.472 us; speedup vs baseline: 1.0018x; 1.0018x over previous
//
#include <hip/hip_runtime.h>

// ---------------------------------------------------------------------------
// AttentionHead: GroupNorm -> QKV 1x1 conv -> softmax attention -> 1x1 conv.
// Round 17: barrier-count attack. KVBLK 64 -> 128: 4 barriers/wave instead
// of 8 (the only structural knob never varied; r15/r16 proved LDS traffic,
// ILP and occupancy are not binding). Tile 32KB, dbuf 64KB LDS, 2 blocks/CU.
// Tile body = r15's verified dual-chain processed twice (4 m-groups).
// gn_stats / gn_qkv / out_proj byte-identical to r15 (63.5us verified).
// ---------------------------------------------------------------------------

#define B_ 4
#define C_ 64
#define D_ 64
#define N_ 4096

using bf16x8 = __attribute__((ext_vector_type(8))) short;     // 8 bf16 = 4 VGPR
using u16x8  = __attribute__((ext_vector_type(8))) unsigned short;
using u32x4  = __attribute__((ext_vector_type(4))) unsigned int;
using f32x16 = __attribute__((ext_vector_type(16))) float;
using h16x8  = __attribute__((ext_vector_type(8))) _Float16;

// round-to-nearest-even f32 -> bf16 bits
__device__ __forceinline__ unsigned short f2bf(float f) {
    unsigned u = __builtin_bit_cast(unsigned, f);
    u = (u + 0x7FFFu + ((u >> 16) & 1u)) >> 16;
    return (unsigned short)u;
}

// single-instruction exp2: builtin (backend-hazard-managed) or asm + s_nop
#if __has_builtin(__builtin_amdgcn_exp2f)
__device__ __forceinline__ float fast_exp2(float x) {
    return __builtin_amdgcn_exp2f(x);
}
#else
__device__ __forceinline__ float fast_exp2(float x) {
    float r;
    asm volatile("v_exp_f32 %0, %1\n\ts_nop 1" : "=v"(r) : "v"(x));
    return r;
}
#endif

// async global->LDS, 16B per lane (lds dst wave-uniform base, +lane*16)
__device__ __forceinline__ void gload16(const void* g, void* l) {
    __builtin_amdgcn_global_load_lds(
        (const __attribute__((address_space(1))) unsigned int*)g,
        (__attribute__((address_space(3))) unsigned int*)l, 16, 0, 0);
}

// ---------------------------------------------------------------------------
// Kernel 1: per-(b,c) mean / rsqrt(var+eps) over H*W = 4096
// ---------------------------------------------------------------------------
__global__ __launch_bounds__(1024)
void gn_stats_kernel(const float* __restrict__ x, float* __restrict__ stats) {
    __shared__ float red[32];
    const int bx  = blockIdx.x;
    const int tid = threadIdx.x;
    const float4* xp = (const float4*)(x + (size_t)bx * N_);
    float4 v = xp[tid];
    float s = (v.x + v.y) + (v.z + v.w);
    float q = (v.x * v.x + v.y * v.y) + (v.z * v.z + v.w * v.w);
#pragma unroll
    for (int off = 1; off < 64; off <<= 1) {
        s += __shfl_xor(s, off);
        q += __shfl_xor(q, off);
    }
    const int w = tid >> 6;
    if ((tid & 63) == 0) { red[w * 2] = s; red[w * 2 + 1] = q; }
    __syncthreads();
    if (w == 0) {
        const int lane = tid & 63;
        float sl = (lane < 16) ? red[lane * 2] : 0.f;
        float ql = (lane < 16) ? red[lane * 2 + 1] : 0.f;
#pragma unroll
        for (int off = 1; off < 16; off <<= 1) {
            sl += __shfl_xor(sl, off);
            ql += __shfl_xor(ql, off);
        }
        if (lane == 0) {
            float mu  = sl * (1.f / 4096.f);
            float var = ql * (1.f / 4096.f) - mu * mu;
            var = fmaxf(var, 0.f);
            stats[bx * 2]     = mu;
            stats[bx * 2 + 1] = 1.f / sqrtf(var + 1e-5f);
        }
    }
}

// ---------------------------------------------------------------------------
// Kernel 2: GroupNorm apply + QKV projections -> MFMA-frag layouts (r7).
// ---------------------------------------------------------------------------
__global__ __launch_bounds__(512)
void gn_qkv_kernel(const float* __restrict__ x, const float* __restrict__ stats,
                   const float* __restrict__ gnw, const float* __restrict__ gnb,
                   const float* __restrict__ wq, const float* __restrict__ bq,
                   const float* __restrict__ wk, const float* __restrict__ bk,
                   const float* __restrict__ wv, const float* __restrict__ bv,
                   unsigned short* __restrict__ Qt, unsigned short* __restrict__ Kf,
                   unsigned short* __restrict__ Vf) {
    __shared__ float xn[64 * 64];                 // [c][n] 16 KB
    __shared__ __align__(16) char vs[64 * 128];   // [m][d] bf16, XOR-swizzled, 8 KB
    const int t  = threadIdx.x;
    const int bx = blockIdx.x;
    const int b  = bx >> 6;
    const int n0 = (bx & 63) * 64;

    // ---- Phase A: load + normalize x tile ----
    {
        const int c  = t >> 3;
        const int nc = (t & 7) * 8;
        const float* xp = x + (size_t)(b * 64 + c) * N_ + n0 + nc;
        float4 xa = *(const float4*)(xp);
        float4 xb = *(const float4*)(xp + 4);
        float mu = stats[(b * 64 + c) * 2];
        float rs = stats[(b * 64 + c) * 2 + 1];
        float gw = gnw[c] * rs;
        float gb = gnb[c] - mu * gw;
        float* xr = xn + c * 64 + nc;
        xr[0] = xa.x * gw + gb; xr[1] = xa.y * gw + gb;
        xr[2] = xa.z * gw + gb; xr[3] = xa.w * gw + gb;
        xr[4] = xb.x * gw + gb; xr[5] = xb.y * gw + gb;
        xr[6] = xb.z * gw + gb; xr[7] = xb.w * gw + gb;
    }
    __syncthreads();

    // ---- Phase B: per (n, 8d) dot products ----
    const int n    = t & 63;
    const int dblk = __builtin_amdgcn_readfirstlane(t >> 6);
    const int d0   = dblk * 8;

    float aq[8], ak[8], av[8];
#pragma unroll
    for (int i = 0; i < 8; ++i) { aq[i] = 0.f; ak[i] = 0.f; av[i] = 0.f; }

#pragma unroll 4
    for (int c = 0; c < 64; ++c) {
        const float xv = xn[c * 64 + n];
#pragma unroll
        for (int i = 0; i < 8; ++i) {
            aq[i] += wq[(d0 + i) * 64 + c] * xv;
            ak[i] += wk[(d0 + i) * 64 + c] * xv;
            av[i] += wv[(d0 + i) * 64 + c] * xv;
        }
    }

    const float QS = 0.18033688011112042f;  // 0.125 * log2(e): exp2-domain logits
    const int m = n0 + n;
    u16x8 qv, kv, vb;
#pragma unroll
    for (int i = 0; i < 8; ++i) {
        qv[i] = f2bf((aq[i] + bq[d0 + i]) * QS);
        kv[i] = f2bf(ak[i] + bk[d0 + i]);
        vb[i] = f2bf(av[i] + bv[d0 + i]);
    }
    // Q: [n][d] row store (16B)
    *(u16x8*)(Qt + ((size_t)(b * N_ + m)) * 64 + d0) = qv;
    // K: direct frag store
    {
        const int kc = dblk >> 1, h = dblk & 1, mt = m >> 5;
        *(u16x8*)(Kf + ((size_t)((b * 128 + mt) * 4 + kc)) * 512
                     + (h * 32 + (m & 31)) * 8) = kv;
    }
    // V: swizzled LDS stage
    *(u16x8*)(vs + n * 128 + ((dblk * 16) ^ ((n & 7) << 4))) = vb;
    __syncthreads();

    // ---- Phase C: frag-ordered Vf copyout (one 16B store per thread) ----
    {
        const int mc_l = t >> 7;            // 0..3
        const int dt   = (t >> 6) & 1;
        const int lp   = t & 63;
        const int hp   = lp >> 5;
        const int dcol = (lp & 31) + dt * 32;
        const int cbase = (dcol & ~7) * 2;
        const int clow  = (dcol & 7) * 2;
        u16x8 tmp;
#pragma unroll
        for (int j = 0; j < 8; ++j) {
            const int ml = mc_l * 16 + hp * 8 + j;   // ml&7 == j
            tmp[j] = *(const unsigned short*)(
                vs + ml * 128 + (cbase ^ (j << 4)) + clow);
        }
        *(u16x8*)(Vf + ((size_t)((b * 256 + (n0 >> 4) + mc_l) * 2 + dt)) * 512
                     + lp * 8) = tmp;
    }
}

// ---------------------------------------------------------------------------
// Kernel 3: attention, LDS-staged via global_load_lds, 32 q-rows/wave,
// KVBLK=128 (4 m-groups/tile, 4 barriers/wave). grid = 128*S blocks
// (b = bid&3, qb = (bid>>2)&31, s = bid>>7), 256 thr, 2 blocks/CU.
// LDS per buffer: K 16KB (4 groups x 4KB) | V 16KB (4 groups x 4KB); 2 bufs.
// Per 128-m tile: 8 gloads/wave for t+1; 2x (dual-chain m-group pair: 8
// ds_read K -> 2 interleaved 4-MFMA S-chains -> exp2 -> pack -> 8 ds_read V
// -> 8 MFMA O); one barrier.
// ---------------------------------------------------------------------------
__global__ __launch_bounds__(256, 2)
void attn_kernel(const unsigned short* __restrict__ Qt,
                 const unsigned short* __restrict__ Kf,
                 const unsigned short* __restrict__ Vf,
                 _Float16* __restrict__ Opart, float* __restrict__ Lpart,
                 int mspan) {
    __shared__ __align__(16) char smem[2 * 32768];
    const int tid  = threadIdx.x;
    const int lane = tid & 63;
    const int wvu  = __builtin_amdgcn_readfirstlane(tid >> 6);   // wave id 0..3
    const int c    = lane & 31;
    const int h    = lane >> 5;
    const int bid  = blockIdx.x;
    const int b    = bid & 3;
    const int t2   = bid >> 2;
    const int qb   = t2 & 31;
    const int s    = t2 >> 5;
    const int qg0  = qb * 128 + wvu * 32;

    // Q B-frag: lane (q=c, h) holds Q[qg0+c][kc*16 + h*8 + j]
    const unsigned short* qp = Qt + (size_t)(b * N_ + qg0 + c) * 64 + h * 8;
    bf16x8 qa[4];
#pragma unroll
    for (int kc = 0; kc < 4; ++kc) qa[kc] = *(const bf16x8*)(qp + kc * 16);

    f32x16 oacc0, oacc1;
#pragma unroll
    for (int i = 0; i < 16; ++i) { oacc0[i] = 0.f; oacc1[i] = 0.f; }
    float ls00 = 0.f, ls01 = 0.f, ls10 = 0.f, ls11 = 0.f;

    const int NT = mspan >> 7;          // 128-m tiles
    const int mstart = s * mspan;
    const int lof = lane * 16;

    // running staging pointers (advance 16 KB per 128-m tile)
    const char* kTn = (const char*)Kf + (size_t)b * 524288
                      + (size_t)(mstart >> 5) * 4096;
    const char* vTn = (const char*)Vf + (size_t)b * 524288
                      + (size_t)(mstart >> 4) * 2048;

    // ---- prologue: async-stage tile 0 into buf0 (8 chunks/wave) ----
#pragma unroll
    for (int j = 0; j < 4; ++j) {
        gload16(kTn + (wvu + 4 * j) * 1024 + lof, smem + (wvu + 4 * j) * 1024);
        gload16(vTn + (wvu + 4 * j) * 1024 + lof,
                smem + 16384 + (wvu + 4 * j) * 1024);
    }
    __syncthreads();   // drains vmcnt -> tile 0 visible

    for (int t = 0; t < NT; ++t) {
        char* buf = smem + ((t & 1) ? 32768 : 0);
        // ---- issue next-tile async stage into the other buffer ----
        if (t + 1 < NT) {
            kTn += 16384;
            vTn += 16384;
            char* dst = smem + ((t & 1) ? 0 : 32768);
#pragma unroll
            for (int j = 0; j < 4; ++j) {
                gload16(kTn + (wvu + 4 * j) * 1024 + lof,
                        dst + (wvu + 4 * j) * 1024);
                gload16(vTn + (wvu + 4 * j) * 1024 + lof,
                        dst + 16384 + (wvu + 4 * j) * 1024);
            }
        }

        // ---- compute current tile: 4 m-groups as two interleaved pairs ----
#pragma unroll
        for (int gg = 0; gg < 4; gg += 2) {
            const char* kb0 = buf + gg * 4096 + lof;
            const char* kb1 = buf + (gg + 1) * 4096 + lof;
            bf16x8 k00 = *(const bf16x8*)(kb0);
            bf16x8 k01 = *(const bf16x8*)(kb0 + 1024);
            bf16x8 k02 = *(const bf16x8*)(kb0 + 2048);
            bf16x8 k03 = *(const bf16x8*)(kb0 + 3072);
            bf16x8 k10 = *(const bf16x8*)(kb1);
            bf16x8 k11 = *(const bf16x8*)(kb1 + 1024);
            bf16x8 k12 = *(const bf16x8*)(kb1 + 2048);
            bf16x8 k13 = *(const bf16x8*)(kb1 + 3072);
            f32x16 sa0, sa1;
#pragma unroll
            for (int i = 0; i < 16; ++i) { sa0[i] = 0.f; sa1[i] = 0.f; }
            // two independent S-chains, alternating issue
            sa0 = __builtin_amdgcn_mfma_f32_32x32x16_bf16(k00, qa[0], sa0, 0, 0, 0);
            sa1 = __builtin_amdgcn_mfma_f32_32x32x16_bf16(k10, qa[0], sa1, 0, 0, 0);
            sa0 = __builtin_amdgcn_mfma_f32_32x32x16_bf16(k01, qa[1], sa0, 0, 0, 0);
            sa1 = __builtin_amdgcn_mfma_f32_32x32x16_bf16(k11, qa[1], sa1, 0, 0, 0);
            sa0 = __builtin_amdgcn_mfma_f32_32x32x16_bf16(k02, qa[2], sa0, 0, 0, 0);
            sa1 = __builtin_amdgcn_mfma_f32_32x32x16_bf16(k12, qa[2], sa1, 0, 0, 0);
            sa0 = __builtin_amdgcn_mfma_f32_32x32x16_bf16(k03, qa[3], sa0, 0, 0, 0);
            sa1 = __builtin_amdgcn_mfma_f32_32x32x16_bf16(k13, qa[3], sa1, 0, 0, 0);

            // P = exp2(S^T) both groups; 4 independent sum chains
#pragma unroll
            for (int i = 0; i < 16; i += 2) {
                float p00 = fast_exp2(sa0[i]);
                float p01 = fast_exp2(sa0[i + 1]);
                float p10 = fast_exp2(sa1[i]);
                float p11 = fast_exp2(sa1[i + 1]);
                sa0[i] = p00; sa0[i + 1] = p01;
                sa1[i] = p10; sa1[i + 1] = p11;
                ls00 += p00; ls01 += p01;
                ls10 += p10; ls11 += p11;
            }
            // pack both groups to bf16 pairs and swap halves
            unsigned dwa[8], dwb[8];
#pragma unroll
            for (int i = 0; i < 8; ++i) {
                asm("v_cvt_pk_bf16_f32 %0, %1, %2"
                    : "=v"(dwa[i]) : "v"(sa0[2 * i]), "v"(sa0[2 * i + 1]));
                asm("v_cvt_pk_bf16_f32 %0, %1, %2"
                    : "=v"(dwb[i]) : "v"(sa1[2 * i]), "v"(sa1[2 * i + 1]));
            }
            asm("v_permlane32_swap_b32 %0, %1" : "+v"(dwa[0]), "+v"(dwa[2]));
            asm("v_permlane32_swap_b32 %0, %1" : "+v"(dwa[1]), "+v"(dwa[3]));
            asm("v_permlane32_swap_b32 %0, %1" : "+v"(dwa[4]), "+v"(dwa[6]));
            asm("v_permlane32_swap_b32 %0, %1" : "+v"(dwa[5]), "+v"(dwa[7]));
            asm("v_permlane32_swap_b32 %0, %1" : "+v"(dwb[0]), "+v"(dwb[2]));
            asm("v_permlane32_swap_b32 %0, %1" : "+v"(dwb[1]), "+v"(dwb[3]));
            asm("v_permlane32_swap_b32 %0, %1" : "+v"(dwb[4]), "+v"(dwb[6]));
            asm("v_permlane32_swap_b32 %0, %1" : "+v"(dwb[5]), "+v"(dwb[7]));
            bf16x8 pa0 = __builtin_bit_cast(bf16x8, (u32x4){dwa[0], dwa[1], dwa[2], dwa[3]});
            bf16x8 pa1 = __builtin_bit_cast(bf16x8, (u32x4){dwa[4], dwa[5], dwa[6], dwa[7]});
            bf16x8 pb0 = __builtin_bit_cast(bf16x8, (u32x4){dwb[0], dwb[1], dwb[2], dwb[3]});
            bf16x8 pb1 = __builtin_bit_cast(bf16x8, (u32x4){dwb[4], dwb[5], dwb[6], dwb[7]});

            // PV both groups (V groups at +16KB, 4KB per group)
            const char* vb0 = buf + 16384 + gg * 4096 + lof;
            const char* vb1 = buf + 16384 + (gg + 1) * 4096 + lof;
            bf16x8 v00 = *(const bf16x8*)(vb0);
            bf16x8 v01 = *(const bf16x8*)(vb0 + 1024);
            bf16x8 v02 = *(const bf16x8*)(vb0 + 2048);
            bf16x8 v03 = *(const bf16x8*)(vb0 + 3072);
            bf16x8 v10 = *(const bf16x8*)(vb1);
            bf16x8 v11 = *(const bf16x8*)(vb1 + 1024);
            bf16x8 v12 = *(const bf16x8*)(vb1 + 2048);
            bf16x8 v13 = *(const bf16x8*)(vb1 + 3072);
            oacc0 = __builtin_amdgcn_mfma_f32_32x32x16_bf16(v00, pa0, oacc0, 0, 0, 0);
            oacc1 = __builtin_amdgcn_mfma_f32_32x32x16_bf16(v01, pa0, oacc1, 0, 0, 0);
            oacc0 = __builtin_amdgcn_mfma_f32_32x32x16_bf16(v02, pa1, oacc0, 0, 0, 0);
            oacc1 = __builtin_amdgcn_mfma_f32_32x32x16_bf16(v03, pa1, oacc1, 0, 0, 0);
            oacc0 = __builtin_amdgcn_mfma_f32_32x32x16_bf16(v10, pb0, oacc0, 0, 0, 0);
            oacc1 = __builtin_amdgcn_mfma_f32_32x32x16_bf16(v11, pb0, oacc1, 0, 0, 0);
            oacc0 = __builtin_amdgcn_mfma_f32_32x32x16_bf16(v12, pb1, oacc0, 0, 0, 0);
            oacc1 = __builtin_amdgcn_mfma_f32_32x32x16_bf16(v13, pb1, oacc1, 0, 0, 0);
        }

        // one barrier per 128-m tile (4 per wave total)
        __syncthreads();
    }

    // rowsum for col q = own half + other half
    float lsum = (ls00 + ls01) + (ls10 + ls11);
    float rs = lsum + __shfl_xor(lsum, 32);

    const size_t s4b = (size_t)(s * 4 + b);
    _Float16* ob = Opart + (s4b * 64 << 12);
#pragma unroll
    for (int r = 0; r < 16; ++r) {
        const int row = (r & 3) + 8 * (r >> 2) + 4 * h;
        ob[((size_t)row << 12) + qg0 + c]        = (_Float16)oacc0[r];
        ob[((size_t)(row + 32) << 12) + qg0 + c] = (_Float16)oacc1[r];
    }
    if (h == 0)
        Lpart[(s4b << 12) + qg0 + c] = rs;
}

// ---------------------------------------------------------------------------
// Kernel 4: merge fp16 partials, normalize, out = wo @ att + bo (r7).
// ---------------------------------------------------------------------------
__global__ __launch_bounds__(256)
void out_proj_kernel(const _Float16* __restrict__ Opart, const float* __restrict__ Lpart,
                     const float* __restrict__ wo, const float* __restrict__ bo,
                     float* __restrict__ out, int S) {
    __shared__ float invl[32];
    __shared__ float attm[64 * 33];   // [d][n], padded
    const int t  = threadIdx.x;
    const int bx = blockIdx.x;
    const int b  = bx >> 7;
    const int n0 = (bx & 127) * 32;

    if (t < 32) {
        float sum = 0.f;
        for (int s = 0; s < S; ++s)
            sum += Lpart[(((size_t)(s * 4 + b)) << 12) + n0 + t];
        invl[t] = 1.f / sum;
    }
    __syncthreads();

    {   // merge: thread (d = t>>2, 8 n at (t&3)*8); 16B fp16 loads
        const int d  = t >> 2;
        const int nb = (t & 3) * 8;
        float o[8] = {0.f, 0.f, 0.f, 0.f, 0.f, 0.f, 0.f, 0.f};
        for (int s = 0; s < S; ++s) {
            h16x8 v = *(const h16x8*)(
                Opart + (((size_t)((s * 4 + b) * 64 + d)) << 12) + n0 + nb);
#pragma unroll
            for (int j = 0; j < 8; ++j) o[j] += (float)v[j];
        }
#pragma unroll
        for (int j = 0; j < 8; ++j)
            attm[d * 33 + nb + j] = o[j] * invl[nb + j];
    }
    __syncthreads();

    const int nn = t & 31;
    const int e0 = (t >> 5) * 8;
    float acc[8];
#pragma unroll
    for (int i = 0; i < 8; ++i) acc[i] = bo[e0 + i];
#pragma unroll 8
    for (int d = 0; d < 64; ++d) {
        const float xv = attm[d * 33 + nn];
#pragma unroll
        for (int i = 0; i < 8; ++i) acc[i] += wo[(e0 + i) * 64 + d] * xv;
    }
#pragma unroll
    for (int i = 0; i < 8; ++i)
        out[((size_t)(b * 64 + e0 + i) << 12) + n0 + nn] = acc[i];
}

// ---------------------------------------------------------------------------
extern "C" void kernel_launch(void* const* d_in, const int* in_sizes, int n_in,
                              void* d_out, int out_size, void* d_ws, size_t ws_size,
                              hipStream_t stream) {
    const float* x   = (const float*)d_in[0];
    const float* gnw = (const float*)d_in[1];
    const float* gnb = (const float*)d_in[2];
    const float* wq  = (const float*)d_in[3];
    const float* bq  = (const float*)d_in[4];
    const float* wk  = (const float*)d_in[5];
    const float* bk  = (const float*)d_in[6];
    const float* wv  = (const float*)d_in[7];
    const float* bv  = (const float*)d_in[8];
    const float* wo  = (const float*)d_in[9];
    const float* bo  = (const float*)d_in[10];
    float* out = (float*)d_out;

    char* wsb = (char*)d_ws;
    float*          stats = (float*)wsb;                                  //   2 KB
    unsigned short* Qt    = (unsigned short*)(wsb + 2048);                //   2 MB
    unsigned short* Kf    = (unsigned short*)(wsb + 2048 + 2097152);      //   2 MB
    unsigned short* Vf    = (unsigned short*)(wsb + 2048 + 2 * 2097152);  //   2 MB

    const size_t base = 2048 + 3ull * 2097152;
    // per m-split slot: Lpart 4*4096*4 = 64 KB, Opart fp16 4*64*4096*2 = 2 MB
    auto need = [&](int S) {
        return base + (size_t)S * (65536 + 2097152);
    };
    const int S = (ws_size >= need(8)) ? 8
                : (ws_size >= need(4)) ? 4
                : (ws_size >= need(2)) ? 2 : 1;
    const int mspan = N_ / S;   // 512 at S=8 -> NT = 4 tiles of 128 m
    float*    Lpart = (float*)(wsb + base);
    _Float16* Opart = (_Float16*)(wsb + base + (size_t)S * 65536);

    gn_stats_kernel<<<dim3(B_ * C_), dim3(1024), 0, stream>>>(x, stats);
    gn_qkv_kernel<<<dim3(B_ * 64), dim3(512), 0, stream>>>(
        x, stats, gnw, gnb, wq, bq, wk, bk, wv, bv, Qt, Kf, Vf);
    attn_kernel<<<dim3(128 * S), dim3(256), 0, stream>>>(
        Qt, Kf, Vf, Opart, Lpart, mspan);
    out_proj_kernel<<<dim3(B_ * 128), dim3(256), 0, stream>>>(
        Opart, Lpart, wo, bo, out, S);
}

// Round 18
// 61.391 us; speedup vs baseline: 1.0357x; 1.0339x over previous
//
#include <hip/hip_runtime.h>

// ---------------------------------------------------------------------------
// AttentionHead: GroupNorm -> QKV 1x1 conv -> softmax attention -> 1x1 conv.
// Round 18: S=8 -> S=4 m-split (host-side only; kernels byte-identical to
// r17). Halves the fp16 partial round-trip (16 MB -> 8 MB), fits the attn
// grid in ONE residency round (512 blocks = 2/CU x 256 CU, no second wave of
// blocks), same per-CU serial m-work, shorter out_proj merge.
// ---------------------------------------------------------------------------

#define B_ 4
#define C_ 64
#define D_ 64
#define N_ 4096

using bf16x8 = __attribute__((ext_vector_type(8))) short;     // 8 bf16 = 4 VGPR
using u16x8  = __attribute__((ext_vector_type(8))) unsigned short;
using u32x4  = __attribute__((ext_vector_type(4))) unsigned int;
using f32x16 = __attribute__((ext_vector_type(16))) float;
using h16x8  = __attribute__((ext_vector_type(8))) _Float16;

// round-to-nearest-even f32 -> bf16 bits
__device__ __forceinline__ unsigned short f2bf(float f) {
    unsigned u = __builtin_bit_cast(unsigned, f);
    u = (u + 0x7FFFu + ((u >> 16) & 1u)) >> 16;
    return (unsigned short)u;
}

// single-instruction exp2: builtin (backend-hazard-managed) or asm + s_nop
#if __has_builtin(__builtin_amdgcn_exp2f)
__device__ __forceinline__ float fast_exp2(float x) {
    return __builtin_amdgcn_exp2f(x);
}
#else
__device__ __forceinline__ float fast_exp2(float x) {
    float r;
    asm volatile("v_exp_f32 %0, %1\n\ts_nop 1" : "=v"(r) : "v"(x));
    return r;
}
#endif

// async global->LDS, 16B per lane (lds dst wave-uniform base, +lane*16)
__device__ __forceinline__ void gload16(const void* g, void* l) {
    __builtin_amdgcn_global_load_lds(
        (const __attribute__((address_space(1))) unsigned int*)g,
        (__attribute__((address_space(3))) unsigned int*)l, 16, 0, 0);
}

// ---------------------------------------------------------------------------
// Kernel 1: per-(b,c) mean / rsqrt(var+eps) over H*W = 4096
// ---------------------------------------------------------------------------
__global__ __launch_bounds__(1024)
void gn_stats_kernel(const float* __restrict__ x, float* __restrict__ stats) {
    __shared__ float red[32];
    const int bx  = blockIdx.x;
    const int tid = threadIdx.x;
    const float4* xp = (const float4*)(x + (size_t)bx * N_);
    float4 v = xp[tid];
    float s = (v.x + v.y) + (v.z + v.w);
    float q = (v.x * v.x + v.y * v.y) + (v.z * v.z + v.w * v.w);
#pragma unroll
    for (int off = 1; off < 64; off <<= 1) {
        s += __shfl_xor(s, off);
        q += __shfl_xor(q, off);
    }
    const int w = tid >> 6;
    if ((tid & 63) == 0) { red[w * 2] = s; red[w * 2 + 1] = q; }
    __syncthreads();
    if (w == 0) {
        const int lane = tid & 63;
        float sl = (lane < 16) ? red[lane * 2] : 0.f;
        float ql = (lane < 16) ? red[lane * 2 + 1] : 0.f;
#pragma unroll
        for (int off = 1; off < 16; off <<= 1) {
            sl += __shfl_xor(sl, off);
            ql += __shfl_xor(ql, off);
        }
        if (lane == 0) {
            float mu  = sl * (1.f / 4096.f);
            float var = ql * (1.f / 4096.f) - mu * mu;
            var = fmaxf(var, 0.f);
            stats[bx * 2]     = mu;
            stats[bx * 2 + 1] = 1.f / sqrtf(var + 1e-5f);
        }
    }
}

// ---------------------------------------------------------------------------
// Kernel 2: GroupNorm apply + QKV projections -> MFMA-frag layouts (r7).
// ---------------------------------------------------------------------------
__global__ __launch_bounds__(512)
void gn_qkv_kernel(const float* __restrict__ x, const float* __restrict__ stats,
                   const float* __restrict__ gnw, const float* __restrict__ gnb,
                   const float* __restrict__ wq, const float* __restrict__ bq,
                   const float* __restrict__ wk, const float* __restrict__ bk,
                   const float* __restrict__ wv, const float* __restrict__ bv,
                   unsigned short* __restrict__ Qt, unsigned short* __restrict__ Kf,
                   unsigned short* __restrict__ Vf) {
    __shared__ float xn[64 * 64];                 // [c][n] 16 KB
    __shared__ __align__(16) char vs[64 * 128];   // [m][d] bf16, XOR-swizzled, 8 KB
    const int t  = threadIdx.x;
    const int bx = blockIdx.x;
    const int b  = bx >> 6;
    const int n0 = (bx & 63) * 64;

    // ---- Phase A: load + normalize x tile ----
    {
        const int c  = t >> 3;
        const int nc = (t & 7) * 8;
        const float* xp = x + (size_t)(b * 64 + c) * N_ + n0 + nc;
        float4 xa = *(const float4*)(xp);
        float4 xb = *(const float4*)(xp + 4);
        float mu = stats[(b * 64 + c) * 2];
        float rs = stats[(b * 64 + c) * 2 + 1];
        float gw = gnw[c] * rs;
        float gb = gnb[c] - mu * gw;
        float* xr = xn + c * 64 + nc;
        xr[0] = xa.x * gw + gb; xr[1] = xa.y * gw + gb;
        xr[2] = xa.z * gw + gb; xr[3] = xa.w * gw + gb;
        xr[4] = xb.x * gw + gb; xr[5] = xb.y * gw + gb;
        xr[6] = xb.z * gw + gb; xr[7] = xb.w * gw + gb;
    }
    __syncthreads();

    // ---- Phase B: per (n, 8d) dot products ----
    const int n    = t & 63;
    const int dblk = __builtin_amdgcn_readfirstlane(t >> 6);
    const int d0   = dblk * 8;

    float aq[8], ak[8], av[8];
#pragma unroll
    for (int i = 0; i < 8; ++i) { aq[i] = 0.f; ak[i] = 0.f; av[i] = 0.f; }

#pragma unroll 4
    for (int c = 0; c < 64; ++c) {
        const float xv = xn[c * 64 + n];
#pragma unroll
        for (int i = 0; i < 8; ++i) {
            aq[i] += wq[(d0 + i) * 64 + c] * xv;
            ak[i] += wk[(d0 + i) * 64 + c] * xv;
            av[i] += wv[(d0 + i) * 64 + c] * xv;
        }
    }

    const float QS = 0.18033688011112042f;  // 0.125 * log2(e): exp2-domain logits
    const int m = n0 + n;
    u16x8 qv, kv, vb;
#pragma unroll
    for (int i = 0; i < 8; ++i) {
        qv[i] = f2bf((aq[i] + bq[d0 + i]) * QS);
        kv[i] = f2bf(ak[i] + bk[d0 + i]);
        vb[i] = f2bf(av[i] + bv[d0 + i]);
    }
    // Q: [n][d] row store (16B)
    *(u16x8*)(Qt + ((size_t)(b * N_ + m)) * 64 + d0) = qv;
    // K: direct frag store
    {
        const int kc = dblk >> 1, h = dblk & 1, mt = m >> 5;
        *(u16x8*)(Kf + ((size_t)((b * 128 + mt) * 4 + kc)) * 512
                     + (h * 32 + (m & 31)) * 8) = kv;
    }
    // V: swizzled LDS stage
    *(u16x8*)(vs + n * 128 + ((dblk * 16) ^ ((n & 7) << 4))) = vb;
    __syncthreads();

    // ---- Phase C: frag-ordered Vf copyout (one 16B store per thread) ----
    {
        const int mc_l = t >> 7;            // 0..3
        const int dt   = (t >> 6) & 1;
        const int lp   = t & 63;
        const int hp   = lp >> 5;
        const int dcol = (lp & 31) + dt * 32;
        const int cbase = (dcol & ~7) * 2;
        const int clow  = (dcol & 7) * 2;
        u16x8 tmp;
#pragma unroll
        for (int j = 0; j < 8; ++j) {
            const int ml = mc_l * 16 + hp * 8 + j;   // ml&7 == j
            tmp[j] = *(const unsigned short*)(
                vs + ml * 128 + (cbase ^ (j << 4)) + clow);
        }
        *(u16x8*)(Vf + ((size_t)((b * 256 + (n0 >> 4) + mc_l) * 2 + dt)) * 512
                     + lp * 8) = tmp;
    }
}

// ---------------------------------------------------------------------------
// Kernel 3: attention, LDS-staged via global_load_lds, 32 q-rows/wave,
// KVBLK=128 (4 m-groups/tile). grid = 128*S blocks, 256 thr, 2 blocks/CU.
// ---------------------------------------------------------------------------
__global__ __launch_bounds__(256, 2)
void attn_kernel(const unsigned short* __restrict__ Qt,
                 const unsigned short* __restrict__ Kf,
                 const unsigned short* __restrict__ Vf,
                 _Float16* __restrict__ Opart, float* __restrict__ Lpart,
                 int mspan) {
    __shared__ __align__(16) char smem[2 * 32768];
    const int tid  = threadIdx.x;
    const int lane = tid & 63;
    const int wvu  = __builtin_amdgcn_readfirstlane(tid >> 6);   // wave id 0..3
    const int c    = lane & 31;
    const int h    = lane >> 5;
    const int bid  = blockIdx.x;
    const int b    = bid & 3;
    const int t2   = bid >> 2;
    const int qb   = t2 & 31;
    const int s    = t2 >> 5;
    const int qg0  = qb * 128 + wvu * 32;

    // Q B-frag: lane (q=c, h) holds Q[qg0+c][kc*16 + h*8 + j]
    const unsigned short* qp = Qt + (size_t)(b * N_ + qg0 + c) * 64 + h * 8;
    bf16x8 qa[4];
#pragma unroll
    for (int kc = 0; kc < 4; ++kc) qa[kc] = *(const bf16x8*)(qp + kc * 16);

    f32x16 oacc0, oacc1;
#pragma unroll
    for (int i = 0; i < 16; ++i) { oacc0[i] = 0.f; oacc1[i] = 0.f; }
    float ls00 = 0.f, ls01 = 0.f, ls10 = 0.f, ls11 = 0.f;

    const int NT = mspan >> 7;          // 128-m tiles
    const int mstart = s * mspan;
    const int lof = lane * 16;

    // running staging pointers (advance 16 KB per 128-m tile)
    const char* kTn = (const char*)Kf + (size_t)b * 524288
                      + (size_t)(mstart >> 5) * 4096;
    const char* vTn = (const char*)Vf + (size_t)b * 524288
                      + (size_t)(mstart >> 4) * 2048;

    // ---- prologue: async-stage tile 0 into buf0 (8 chunks/wave) ----
#pragma unroll
    for (int j = 0; j < 4; ++j) {
        gload16(kTn + (wvu + 4 * j) * 1024 + lof, smem + (wvu + 4 * j) * 1024);
        gload16(vTn + (wvu + 4 * j) * 1024 + lof,
                smem + 16384 + (wvu + 4 * j) * 1024);
    }
    __syncthreads();   // drains vmcnt -> tile 0 visible

    for (int t = 0; t < NT; ++t) {
        char* buf = smem + ((t & 1) ? 32768 : 0);
        // ---- issue next-tile async stage into the other buffer ----
        if (t + 1 < NT) {
            kTn += 16384;
            vTn += 16384;
            char* dst = smem + ((t & 1) ? 0 : 32768);
#pragma unroll
            for (int j = 0; j < 4; ++j) {
                gload16(kTn + (wvu + 4 * j) * 1024 + lof,
                        dst + (wvu + 4 * j) * 1024);
                gload16(vTn + (wvu + 4 * j) * 1024 + lof,
                        dst + 16384 + (wvu + 4 * j) * 1024);
            }
        }

        // ---- compute current tile: 4 m-groups as two interleaved pairs ----
#pragma unroll
        for (int gg = 0; gg < 4; gg += 2) {
            const char* kb0 = buf + gg * 4096 + lof;
            const char* kb1 = buf + (gg + 1) * 4096 + lof;
            bf16x8 k00 = *(const bf16x8*)(kb0);
            bf16x8 k01 = *(const bf16x8*)(kb0 + 1024);
            bf16x8 k02 = *(const bf16x8*)(kb0 + 2048);
            bf16x8 k03 = *(const bf16x8*)(kb0 + 3072);
            bf16x8 k10 = *(const bf16x8*)(kb1);
            bf16x8 k11 = *(const bf16x8*)(kb1 + 1024);
            bf16x8 k12 = *(const bf16x8*)(kb1 + 2048);
            bf16x8 k13 = *(const bf16x8*)(kb1 + 3072);
            f32x16 sa0, sa1;
#pragma unroll
            for (int i = 0; i < 16; ++i) { sa0[i] = 0.f; sa1[i] = 0.f; }
            // two independent S-chains, alternating issue
            sa0 = __builtin_amdgcn_mfma_f32_32x32x16_bf16(k00, qa[0], sa0, 0, 0, 0);
            sa1 = __builtin_amdgcn_mfma_f32_32x32x16_bf16(k10, qa[0], sa1, 0, 0, 0);
            sa0 = __builtin_amdgcn_mfma_f32_32x32x16_bf16(k01, qa[1], sa0, 0, 0, 0);
            sa1 = __builtin_amdgcn_mfma_f32_32x32x16_bf16(k11, qa[1], sa1, 0, 0, 0);
            sa0 = __builtin_amdgcn_mfma_f32_32x32x16_bf16(k02, qa[2], sa0, 0, 0, 0);
            sa1 = __builtin_amdgcn_mfma_f32_32x32x16_bf16(k12, qa[2], sa1, 0, 0, 0);
            sa0 = __builtin_amdgcn_mfma_f32_32x32x16_bf16(k03, qa[3], sa0, 0, 0, 0);
            sa1 = __builtin_amdgcn_mfma_f32_32x32x16_bf16(k13, qa[3], sa1, 0, 0, 0);

            // P = exp2(S^T) both groups; 4 independent sum chains
#pragma unroll
            for (int i = 0; i < 16; i += 2) {
                float p00 = fast_exp2(sa0[i]);
                float p01 = fast_exp2(sa0[i + 1]);
                float p10 = fast_exp2(sa1[i]);
                float p11 = fast_exp2(sa1[i + 1]);
                sa0[i] = p00; sa0[i + 1] = p01;
                sa1[i] = p10; sa1[i + 1] = p11;
                ls00 += p00; ls01 += p01;
                ls10 += p10; ls11 += p11;
            }
            // pack both groups to bf16 pairs and swap halves
            unsigned dwa[8], dwb[8];
#pragma unroll
            for (int i = 0; i < 8; ++i) {
                asm("v_cvt_pk_bf16_f32 %0, %1, %2"
                    : "=v"(dwa[i]) : "v"(sa0[2 * i]), "v"(sa0[2 * i + 1]));
                asm("v_cvt_pk_bf16_f32 %0, %1, %2"
                    : "=v"(dwb[i]) : "v"(sa1[2 * i]), "v"(sa1[2 * i + 1]));
            }
            asm("v_permlane32_swap_b32 %0, %1" : "+v"(dwa[0]), "+v"(dwa[2]));
            asm("v_permlane32_swap_b32 %0, %1" : "+v"(dwa[1]), "+v"(dwa[3]));
            asm("v_permlane32_swap_b32 %0, %1" : "+v"(dwa[4]), "+v"(dwa[6]));
            asm("v_permlane32_swap_b32 %0, %1" : "+v"(dwa[5]), "+v"(dwa[7]));
            asm("v_permlane32_swap_b32 %0, %1" : "+v"(dwb[0]), "+v"(dwb[2]));
            asm("v_permlane32_swap_b32 %0, %1" : "+v"(dwb[1]), "+v"(dwb[3]));
            asm("v_permlane32_swap_b32 %0, %1" : "+v"(dwb[4]), "+v"(dwb[6]));
            asm("v_permlane32_swap_b32 %0, %1" : "+v"(dwb[5]), "+v"(dwb[7]));
            bf16x8 pa0 = __builtin_bit_cast(bf16x8, (u32x4){dwa[0], dwa[1], dwa[2], dwa[3]});
            bf16x8 pa1 = __builtin_bit_cast(bf16x8, (u32x4){dwa[4], dwa[5], dwa[6], dwa[7]});
            bf16x8 pb0 = __builtin_bit_cast(bf16x8, (u32x4){dwb[0], dwb[1], dwb[2], dwb[3]});
            bf16x8 pb1 = __builtin_bit_cast(bf16x8, (u32x4){dwb[4], dwb[5], dwb[6], dwb[7]});

            // PV both groups (V groups at +16KB, 4KB per group)
            const char* vb0 = buf + 16384 + gg * 4096 + lof;
            const char* vb1 = buf + 16384 + (gg + 1) * 4096 + lof;
            bf16x8 v00 = *(const bf16x8*)(vb0);
            bf16x8 v01 = *(const bf16x8*)(vb0 + 1024);
            bf16x8 v02 = *(const bf16x8*)(vb0 + 2048);
            bf16x8 v03 = *(const bf16x8*)(vb0 + 3072);
            bf16x8 v10 = *(const bf16x8*)(vb1);
            bf16x8 v11 = *(const bf16x8*)(vb1 + 1024);
            bf16x8 v12 = *(const bf16x8*)(vb1 + 2048);
            bf16x8 v13 = *(const bf16x8*)(vb1 + 3072);
            oacc0 = __builtin_amdgcn_mfma_f32_32x32x16_bf16(v00, pa0, oacc0, 0, 0, 0);
            oacc1 = __builtin_amdgcn_mfma_f32_32x32x16_bf16(v01, pa0, oacc1, 0, 0, 0);
            oacc0 = __builtin_amdgcn_mfma_f32_32x32x16_bf16(v02, pa1, oacc0, 0, 0, 0);
            oacc1 = __builtin_amdgcn_mfma_f32_32x32x16_bf16(v03, pa1, oacc1, 0, 0, 0);
            oacc0 = __builtin_amdgcn_mfma_f32_32x32x16_bf16(v10, pb0, oacc0, 0, 0, 0);
            oacc1 = __builtin_amdgcn_mfma_f32_32x32x16_bf16(v11, pb0, oacc1, 0, 0, 0);
            oacc0 = __builtin_amdgcn_mfma_f32_32x32x16_bf16(v12, pb1, oacc0, 0, 0, 0);
            oacc1 = __builtin_amdgcn_mfma_f32_32x32x16_bf16(v13, pb1, oacc1, 0, 0, 0);
        }

        // one barrier per 128-m tile
        __syncthreads();
    }

    // rowsum for col q = own half + other half
    float lsum = (ls00 + ls01) + (ls10 + ls11);
    float rs = lsum + __shfl_xor(lsum, 32);

    const size_t s4b = (size_t)(s * 4 + b);
    _Float16* ob = Opart + (s4b * 64 << 12);
#pragma unroll
    for (int r = 0; r < 16; ++r) {
        const int row = (r & 3) + 8 * (r >> 2) + 4 * h;
        ob[((size_t)row << 12) + qg0 + c]        = (_Float16)oacc0[r];
        ob[((size_t)(row + 32) << 12) + qg0 + c] = (_Float16)oacc1[r];
    }
    if (h == 0)
        Lpart[(s4b << 12) + qg0 + c] = rs;
}

// ---------------------------------------------------------------------------
// Kernel 4: merge fp16 partials, normalize, out = wo @ att + bo (r7).
// ---------------------------------------------------------------------------
__global__ __launch_bounds__(256)
void out_proj_kernel(const _Float16* __restrict__ Opart, const float* __restrict__ Lpart,
                     const float* __restrict__ wo, const float* __restrict__ bo,
                     float* __restrict__ out, int S) {
    __shared__ float invl[32];
    __shared__ float attm[64 * 33];   // [d][n], padded
    const int t  = threadIdx.x;
    const int bx = blockIdx.x;
    const int b  = bx >> 7;
    const int n0 = (bx & 127) * 32;

    if (t < 32) {
        float sum = 0.f;
        for (int s = 0; s < S; ++s)
            sum += Lpart[(((size_t)(s * 4 + b)) << 12) + n0 + t];
        invl[t] = 1.f / sum;
    }
    __syncthreads();

    {   // merge: thread (d = t>>2, 8 n at (t&3)*8); 16B fp16 loads
        const int d  = t >> 2;
        const int nb = (t & 3) * 8;
        float o[8] = {0.f, 0.f, 0.f, 0.f, 0.f, 0.f, 0.f, 0.f};
        for (int s = 0; s < S; ++s) {
            h16x8 v = *(const h16x8*)(
                Opart + (((size_t)((s * 4 + b) * 64 + d)) << 12) + n0 + nb);
#pragma unroll
            for (int j = 0; j < 8; ++j) o[j] += (float)v[j];
        }
#pragma unroll
        for (int j = 0; j < 8; ++j)
            attm[d * 33 + nb + j] = o[j] * invl[nb + j];
    }
    __syncthreads();

    const int nn = t & 31;
    const int e0 = (t >> 5) * 8;
    float acc[8];
#pragma unroll
    for (int i = 0; i < 8; ++i) acc[i] = bo[e0 + i];
#pragma unroll 8
    for (int d = 0; d < 64; ++d) {
        const float xv = attm[d * 33 + nn];
#pragma unroll
        for (int i = 0; i < 8; ++i) acc[i] += wo[(e0 + i) * 64 + d] * xv;
    }
#pragma unroll
    for (int i = 0; i < 8; ++i)
        out[((size_t)(b * 64 + e0 + i) << 12) + n0 + nn] = acc[i];
}

// ---------------------------------------------------------------------------
extern "C" void kernel_launch(void* const* d_in, const int* in_sizes, int n_in,
                              void* d_out, int out_size, void* d_ws, size_t ws_size,
                              hipStream_t stream) {
    const float* x   = (const float*)d_in[0];
    const float* gnw = (const float*)d_in[1];
    const float* gnb = (const float*)d_in[2];
    const float* wq  = (const float*)d_in[3];
    const float* bq  = (const float*)d_in[4];
    const float* wk  = (const float*)d_in[5];
    const float* bk  = (const float*)d_in[6];
    const float* wv  = (const float*)d_in[7];
    const float* bv  = (const float*)d_in[8];
    const float* wo  = (const float*)d_in[9];
    const float* bo  = (const float*)d_in[10];
    float* out = (float*)d_out;

    char* wsb = (char*)d_ws;
    float*          stats = (float*)wsb;                                  //   2 KB
    unsigned short* Qt    = (unsigned short*)(wsb + 2048);                //   2 MB
    unsigned short* Kf    = (unsigned short*)(wsb + 2048 + 2097152);      //   2 MB
    unsigned short* Vf    = (unsigned short*)(wsb + 2048 + 2 * 2097152);  //   2 MB

    const size_t base = 2048 + 3ull * 2097152;
    // per m-split slot: Lpart 4*4096*4 = 64 KB, Opart fp16 4*64*4096*2 = 2 MB
    auto need = [&](int S) {
        return base + (size_t)S * (65536 + 2097152);
    };
    // S=4: one residency round (512 blocks = 2/CU), half the partial traffic
    // of S=8, same per-CU serial m-work (2 blocks x 1024 m).
    const int S = (ws_size >= need(4)) ? 4
                : (ws_size >= need(2)) ? 2 : 1;
    const int mspan = N_ / S;   // 1024 at S=4 -> NT = 8 tiles of 128 m
    float*    Lpart = (float*)(wsb + base);
    _Float16* Opart = (_Float16*)(wsb + base + (size_t)S * 65536);

    gn_stats_kernel<<<dim3(B_ * C_), dim3(1024), 0, stream>>>(x, stats);
    gn_qkv_kernel<<<dim3(B_ * 64), dim3(512), 0, stream>>>(
        x, stats, gnw, gnb, wq, bq, wk, bk, wv, bv, Qt, Kf, Vf);
    attn_kernel<<<dim3(128 * S), dim3(256), 0, stream>>>(
        Qt, Kf, Vf, Opart, Lpart, mspan);
    out_proj_kernel<<<dim3(B_ * 128), dim3(256), 0, stream>>>(
        Opart, Lpart, wo, bo, out, S);
}

// Round 19
// 59.831 us; speedup vs baseline: 1.0627x; 1.0261x over previous
//
#include <hip/hip_runtime.h>

// ---------------------------------------------------------------------------
// AttentionHead: GroupNorm -> QKV 1x1 conv -> softmax attention -> 1x1 conv.
// Round 19: S=4 -> S=2 (host-side only; kernels byte-identical to r18).
// Partial round-trip 8 MB -> 4 MB, out_proj merge halves; attn grid 256
// blocks = 1/CU (per-wave work doubles, amortizing prologue). r16 measured
// occupancy halving as null; traffic trend (r18: -2.1us) says net win.
// ---------------------------------------------------------------------------

#define B_ 4
#define C_ 64
#define D_ 64
#define N_ 4096

using bf16x8 = __attribute__((ext_vector_type(8))) short;     // 8 bf16 = 4 VGPR
using u16x8  = __attribute__((ext_vector_type(8))) unsigned short;
using u32x4  = __attribute__((ext_vector_type(4))) unsigned int;
using f32x16 = __attribute__((ext_vector_type(16))) float;
using h16x8  = __attribute__((ext_vector_type(8))) _Float16;

// round-to-nearest-even f32 -> bf16 bits
__device__ __forceinline__ unsigned short f2bf(float f) {
    unsigned u = __builtin_bit_cast(unsigned, f);
    u = (u + 0x7FFFu + ((u >> 16) & 1u)) >> 16;
    return (unsigned short)u;
}

// single-instruction exp2: builtin (backend-hazard-managed) or asm + s_nop
#if __has_builtin(__builtin_amdgcn_exp2f)
__device__ __forceinline__ float fast_exp2(float x) {
    return __builtin_amdgcn_exp2f(x);
}
#else
__device__ __forceinline__ float fast_exp2(float x) {
    float r;
    asm volatile("v_exp_f32 %0, %1\n\ts_nop 1" : "=v"(r) : "v"(x));
    return r;
}
#endif

// async global->LDS, 16B per lane (lds dst wave-uniform base, +lane*16)
__device__ __forceinline__ void gload16(const void* g, void* l) {
    __builtin_amdgcn_global_load_lds(
        (const __attribute__((address_space(1))) unsigned int*)g,
        (__attribute__((address_space(3))) unsigned int*)l, 16, 0, 0);
}

// ---------------------------------------------------------------------------
// Kernel 1: per-(b,c) mean / rsqrt(var+eps) over H*W = 4096
// ---------------------------------------------------------------------------
__global__ __launch_bounds__(1024)
void gn_stats_kernel(const float* __restrict__ x, float* __restrict__ stats) {
    __shared__ float red[32];
    const int bx  = blockIdx.x;
    const int tid = threadIdx.x;
    const float4* xp = (const float4*)(x + (size_t)bx * N_);
    float4 v = xp[tid];
    float s = (v.x + v.y) + (v.z + v.w);
    float q = (v.x * v.x + v.y * v.y) + (v.z * v.z + v.w * v.w);
#pragma unroll
    for (int off = 1; off < 64; off <<= 1) {
        s += __shfl_xor(s, off);
        q += __shfl_xor(q, off);
    }
    const int w = tid >> 6;
    if ((tid & 63) == 0) { red[w * 2] = s; red[w * 2 + 1] = q; }
    __syncthreads();
    if (w == 0) {
        const int lane = tid & 63;
        float sl = (lane < 16) ? red[lane * 2] : 0.f;
        float ql = (lane < 16) ? red[lane * 2 + 1] : 0.f;
#pragma unroll
        for (int off = 1; off < 16; off <<= 1) {
            sl += __shfl_xor(sl, off);
            ql += __shfl_xor(ql, off);
        }
        if (lane == 0) {
            float mu  = sl * (1.f / 4096.f);
            float var = ql * (1.f / 4096.f) - mu * mu;
            var = fmaxf(var, 0.f);
            stats[bx * 2]     = mu;
            stats[bx * 2 + 1] = 1.f / sqrtf(var + 1e-5f);
        }
    }
}

// ---------------------------------------------------------------------------
// Kernel 2: GroupNorm apply + QKV projections -> MFMA-frag layouts (r7).
// ---------------------------------------------------------------------------
__global__ __launch_bounds__(512)
void gn_qkv_kernel(const float* __restrict__ x, const float* __restrict__ stats,
                   const float* __restrict__ gnw, const float* __restrict__ gnb,
                   const float* __restrict__ wq, const float* __restrict__ bq,
                   const float* __restrict__ wk, const float* __restrict__ bk,
                   const float* __restrict__ wv, const float* __restrict__ bv,
                   unsigned short* __restrict__ Qt, unsigned short* __restrict__ Kf,
                   unsigned short* __restrict__ Vf) {
    __shared__ float xn[64 * 64];                 // [c][n] 16 KB
    __shared__ __align__(16) char vs[64 * 128];   // [m][d] bf16, XOR-swizzled, 8 KB
    const int t  = threadIdx.x;
    const int bx = blockIdx.x;
    const int b  = bx >> 6;
    const int n0 = (bx & 63) * 64;

    // ---- Phase A: load + normalize x tile ----
    {
        const int c  = t >> 3;
        const int nc = (t & 7) * 8;
        const float* xp = x + (size_t)(b * 64 + c) * N_ + n0 + nc;
        float4 xa = *(const float4*)(xp);
        float4 xb = *(const float4*)(xp + 4);
        float mu = stats[(b * 64 + c) * 2];
        float rs = stats[(b * 64 + c) * 2 + 1];
        float gw = gnw[c] * rs;
        float gb = gnb[c] - mu * gw;
        float* xr = xn + c * 64 + nc;
        xr[0] = xa.x * gw + gb; xr[1] = xa.y * gw + gb;
        xr[2] = xa.z * gw + gb; xr[3] = xa.w * gw + gb;
        xr[4] = xb.x * gw + gb; xr[5] = xb.y * gw + gb;
        xr[6] = xb.z * gw + gb; xr[7] = xb.w * gw + gb;
    }
    __syncthreads();

    // ---- Phase B: per (n, 8d) dot products ----
    const int n    = t & 63;
    const int dblk = __builtin_amdgcn_readfirstlane(t >> 6);
    const int d0   = dblk * 8;

    float aq[8], ak[8], av[8];
#pragma unroll
    for (int i = 0; i < 8; ++i) { aq[i] = 0.f; ak[i] = 0.f; av[i] = 0.f; }

#pragma unroll 4
    for (int c = 0; c < 64; ++c) {
        const float xv = xn[c * 64 + n];
#pragma unroll
        for (int i = 0; i < 8; ++i) {
            aq[i] += wq[(d0 + i) * 64 + c] * xv;
            ak[i] += wk[(d0 + i) * 64 + c] * xv;
            av[i] += wv[(d0 + i) * 64 + c] * xv;
        }
    }

    const float QS = 0.18033688011112042f;  // 0.125 * log2(e): exp2-domain logits
    const int m = n0 + n;
    u16x8 qv, kv, vb;
#pragma unroll
    for (int i = 0; i < 8; ++i) {
        qv[i] = f2bf((aq[i] + bq[d0 + i]) * QS);
        kv[i] = f2bf(ak[i] + bk[d0 + i]);
        vb[i] = f2bf(av[i] + bv[d0 + i]);
    }
    // Q: [n][d] row store (16B)
    *(u16x8*)(Qt + ((size_t)(b * N_ + m)) * 64 + d0) = qv;
    // K: direct frag store
    {
        const int kc = dblk >> 1, h = dblk & 1, mt = m >> 5;
        *(u16x8*)(Kf + ((size_t)((b * 128 + mt) * 4 + kc)) * 512
                     + (h * 32 + (m & 31)) * 8) = kv;
    }
    // V: swizzled LDS stage
    *(u16x8*)(vs + n * 128 + ((dblk * 16) ^ ((n & 7) << 4))) = vb;
    __syncthreads();

    // ---- Phase C: frag-ordered Vf copyout (one 16B store per thread) ----
    {
        const int mc_l = t >> 7;            // 0..3
        const int dt   = (t >> 6) & 1;
        const int lp   = t & 63;
        const int hp   = lp >> 5;
        const int dcol = (lp & 31) + dt * 32;
        const int cbase = (dcol & ~7) * 2;
        const int clow  = (dcol & 7) * 2;
        u16x8 tmp;
#pragma unroll
        for (int j = 0; j < 8; ++j) {
            const int ml = mc_l * 16 + hp * 8 + j;   // ml&7 == j
            tmp[j] = *(const unsigned short*)(
                vs + ml * 128 + (cbase ^ (j << 4)) + clow);
        }
        *(u16x8*)(Vf + ((size_t)((b * 256 + (n0 >> 4) + mc_l) * 2 + dt)) * 512
                     + lp * 8) = tmp;
    }
}

// ---------------------------------------------------------------------------
// Kernel 3: attention, LDS-staged via global_load_lds, 32 q-rows/wave,
// KVBLK=128 (4 m-groups/tile). grid = 128*S blocks, 256 thr.
// ---------------------------------------------------------------------------
__global__ __launch_bounds__(256, 2)
void attn_kernel(const unsigned short* __restrict__ Qt,
                 const unsigned short* __restrict__ Kf,
                 const unsigned short* __restrict__ Vf,
                 _Float16* __restrict__ Opart, float* __restrict__ Lpart,
                 int mspan) {
    __shared__ __align__(16) char smem[2 * 32768];
    const int tid  = threadIdx.x;
    const int lane = tid & 63;
    const int wvu  = __builtin_amdgcn_readfirstlane(tid >> 6);   // wave id 0..3
    const int c    = lane & 31;
    const int h    = lane >> 5;
    const int bid  = blockIdx.x;
    const int b    = bid & 3;
    const int t2   = bid >> 2;
    const int qb   = t2 & 31;
    const int s    = t2 >> 5;
    const int qg0  = qb * 128 + wvu * 32;

    // Q B-frag: lane (q=c, h) holds Q[qg0+c][kc*16 + h*8 + j]
    const unsigned short* qp = Qt + (size_t)(b * N_ + qg0 + c) * 64 + h * 8;
    bf16x8 qa[4];
#pragma unroll
    for (int kc = 0; kc < 4; ++kc) qa[kc] = *(const bf16x8*)(qp + kc * 16);

    f32x16 oacc0, oacc1;
#pragma unroll
    for (int i = 0; i < 16; ++i) { oacc0[i] = 0.f; oacc1[i] = 0.f; }
    float ls00 = 0.f, ls01 = 0.f, ls10 = 0.f, ls11 = 0.f;

    const int NT = mspan >> 7;          // 128-m tiles
    const int mstart = s * mspan;
    const int lof = lane * 16;

    // running staging pointers (advance 16 KB per 128-m tile)
    const char* kTn = (const char*)Kf + (size_t)b * 524288
                      + (size_t)(mstart >> 5) * 4096;
    const char* vTn = (const char*)Vf + (size_t)b * 524288
                      + (size_t)(mstart >> 4) * 2048;

    // ---- prologue: async-stage tile 0 into buf0 (8 chunks/wave) ----
#pragma unroll
    for (int j = 0; j < 4; ++j) {
        gload16(kTn + (wvu + 4 * j) * 1024 + lof, smem + (wvu + 4 * j) * 1024);
        gload16(vTn + (wvu + 4 * j) * 1024 + lof,
                smem + 16384 + (wvu + 4 * j) * 1024);
    }
    __syncthreads();   // drains vmcnt -> tile 0 visible

    for (int t = 0; t < NT; ++t) {
        char* buf = smem + ((t & 1) ? 32768 : 0);
        // ---- issue next-tile async stage into the other buffer ----
        if (t + 1 < NT) {
            kTn += 16384;
            vTn += 16384;
            char* dst = smem + ((t & 1) ? 0 : 32768);
#pragma unroll
            for (int j = 0; j < 4; ++j) {
                gload16(kTn + (wvu + 4 * j) * 1024 + lof,
                        dst + (wvu + 4 * j) * 1024);
                gload16(vTn + (wvu + 4 * j) * 1024 + lof,
                        dst + 16384 + (wvu + 4 * j) * 1024);
            }
        }

        // ---- compute current tile: 4 m-groups as two interleaved pairs ----
#pragma unroll
        for (int gg = 0; gg < 4; gg += 2) {
            const char* kb0 = buf + gg * 4096 + lof;
            const char* kb1 = buf + (gg + 1) * 4096 + lof;
            bf16x8 k00 = *(const bf16x8*)(kb0);
            bf16x8 k01 = *(const bf16x8*)(kb0 + 1024);
            bf16x8 k02 = *(const bf16x8*)(kb0 + 2048);
            bf16x8 k03 = *(const bf16x8*)(kb0 + 3072);
            bf16x8 k10 = *(const bf16x8*)(kb1);
            bf16x8 k11 = *(const bf16x8*)(kb1 + 1024);
            bf16x8 k12 = *(const bf16x8*)(kb1 + 2048);
            bf16x8 k13 = *(const bf16x8*)(kb1 + 3072);
            f32x16 sa0, sa1;
#pragma unroll
            for (int i = 0; i < 16; ++i) { sa0[i] = 0.f; sa1[i] = 0.f; }
            // two independent S-chains, alternating issue
            sa0 = __builtin_amdgcn_mfma_f32_32x32x16_bf16(k00, qa[0], sa0, 0, 0, 0);
            sa1 = __builtin_amdgcn_mfma_f32_32x32x16_bf16(k10, qa[0], sa1, 0, 0, 0);
            sa0 = __builtin_amdgcn_mfma_f32_32x32x16_bf16(k01, qa[1], sa0, 0, 0, 0);
            sa1 = __builtin_amdgcn_mfma_f32_32x32x16_bf16(k11, qa[1], sa1, 0, 0, 0);
            sa0 = __builtin_amdgcn_mfma_f32_32x32x16_bf16(k02, qa[2], sa0, 0, 0, 0);
            sa1 = __builtin_amdgcn_mfma_f32_32x32x16_bf16(k12, qa[2], sa1, 0, 0, 0);
            sa0 = __builtin_amdgcn_mfma_f32_32x32x16_bf16(k03, qa[3], sa0, 0, 0, 0);
            sa1 = __builtin_amdgcn_mfma_f32_32x32x16_bf16(k13, qa[3], sa1, 0, 0, 0);

            // P = exp2(S^T) both groups; 4 independent sum chains
#pragma unroll
            for (int i = 0; i < 16; i += 2) {
                float p00 = fast_exp2(sa0[i]);
                float p01 = fast_exp2(sa0[i + 1]);
                float p10 = fast_exp2(sa1[i]);
                float p11 = fast_exp2(sa1[i + 1]);
                sa0[i] = p00; sa0[i + 1] = p01;
                sa1[i] = p10; sa1[i + 1] = p11;
                ls00 += p00; ls01 += p01;
                ls10 += p10; ls11 += p11;
            }
            // pack both groups to bf16 pairs and swap halves
            unsigned dwa[8], dwb[8];
#pragma unroll
            for (int i = 0; i < 8; ++i) {
                asm("v_cvt_pk_bf16_f32 %0, %1, %2"
                    : "=v"(dwa[i]) : "v"(sa0[2 * i]), "v"(sa0[2 * i + 1]));
                asm("v_cvt_pk_bf16_f32 %0, %1, %2"
                    : "=v"(dwb[i]) : "v"(sa1[2 * i]), "v"(sa1[2 * i + 1]));
            }
            asm("v_permlane32_swap_b32 %0, %1" : "+v"(dwa[0]), "+v"(dwa[2]));
            asm("v_permlane32_swap_b32 %0, %1" : "+v"(dwa[1]), "+v"(dwa[3]));
            asm("v_permlane32_swap_b32 %0, %1" : "+v"(dwa[4]), "+v"(dwa[6]));
            asm("v_permlane32_swap_b32 %0, %1" : "+v"(dwa[5]), "+v"(dwa[7]));
            asm("v_permlane32_swap_b32 %0, %1" : "+v"(dwb[0]), "+v"(dwb[2]));
            asm("v_permlane32_swap_b32 %0, %1" : "+v"(dwb[1]), "+v"(dwb[3]));
            asm("v_permlane32_swap_b32 %0, %1" : "+v"(dwb[4]), "+v"(dwb[6]));
            asm("v_permlane32_swap_b32 %0, %1" : "+v"(dwb[5]), "+v"(dwb[7]));
            bf16x8 pa0 = __builtin_bit_cast(bf16x8, (u32x4){dwa[0], dwa[1], dwa[2], dwa[3]});
            bf16x8 pa1 = __builtin_bit_cast(bf16x8, (u32x4){dwa[4], dwa[5], dwa[6], dwa[7]});
            bf16x8 pb0 = __builtin_bit_cast(bf16x8, (u32x4){dwb[0], dwb[1], dwb[2], dwb[3]});
            bf16x8 pb1 = __builtin_bit_cast(bf16x8, (u32x4){dwb[4], dwb[5], dwb[6], dwb[7]});

            // PV both groups (V groups at +16KB, 4KB per group)
            const char* vb0 = buf + 16384 + gg * 4096 + lof;
            const char* vb1 = buf + 16384 + (gg + 1) * 4096 + lof;
            bf16x8 v00 = *(const bf16x8*)(vb0);
            bf16x8 v01 = *(const bf16x8*)(vb0 + 1024);
            bf16x8 v02 = *(const bf16x8*)(vb0 + 2048);
            bf16x8 v03 = *(const bf16x8*)(vb0 + 3072);
            bf16x8 v10 = *(const bf16x8*)(vb1);
            bf16x8 v11 = *(const bf16x8*)(vb1 + 1024);
            bf16x8 v12 = *(const bf16x8*)(vb1 + 2048);
            bf16x8 v13 = *(const bf16x8*)(vb1 + 3072);
            oacc0 = __builtin_amdgcn_mfma_f32_32x32x16_bf16(v00, pa0, oacc0, 0, 0, 0);
            oacc1 = __builtin_amdgcn_mfma_f32_32x32x16_bf16(v01, pa0, oacc1, 0, 0, 0);
            oacc0 = __builtin_amdgcn_mfma_f32_32x32x16_bf16(v02, pa1, oacc0, 0, 0, 0);
            oacc1 = __builtin_amdgcn_mfma_f32_32x32x16_bf16(v03, pa1, oacc1, 0, 0, 0);
            oacc0 = __builtin_amdgcn_mfma_f32_32x32x16_bf16(v10, pb0, oacc0, 0, 0, 0);
            oacc1 = __builtin_amdgcn_mfma_f32_32x32x16_bf16(v11, pb0, oacc1, 0, 0, 0);
            oacc0 = __builtin_amdgcn_mfma_f32_32x32x16_bf16(v12, pb1, oacc0, 0, 0, 0);
            oacc1 = __builtin_amdgcn_mfma_f32_32x32x16_bf16(v13, pb1, oacc1, 0, 0, 0);
        }

        // one barrier per 128-m tile
        __syncthreads();
    }

    // rowsum for col q = own half + other half
    float lsum = (ls00 + ls01) + (ls10 + ls11);
    float rs = lsum + __shfl_xor(lsum, 32);

    const size_t s4b = (size_t)(s * 4 + b);
    _Float16* ob = Opart + (s4b * 64 << 12);
#pragma unroll
    for (int r = 0; r < 16; ++r) {
        const int row = (r & 3) + 8 * (r >> 2) + 4 * h;
        ob[((size_t)row << 12) + qg0 + c]        = (_Float16)oacc0[r];
        ob[((size_t)(row + 32) << 12) + qg0 + c] = (_Float16)oacc1[r];
    }
    if (h == 0)
        Lpart[(s4b << 12) + qg0 + c] = rs;
}

// ---------------------------------------------------------------------------
// Kernel 4: merge fp16 partials, normalize, out = wo @ att + bo (r7).
// ---------------------------------------------------------------------------
__global__ __launch_bounds__(256)
void out_proj_kernel(const _Float16* __restrict__ Opart, const float* __restrict__ Lpart,
                     const float* __restrict__ wo, const float* __restrict__ bo,
                     float* __restrict__ out, int S) {
    __shared__ float invl[32];
    __shared__ float attm[64 * 33];   // [d][n], padded
    const int t  = threadIdx.x;
    const int bx = blockIdx.x;
    const int b  = bx >> 7;
    const int n0 = (bx & 127) * 32;

    if (t < 32) {
        float sum = 0.f;
        for (int s = 0; s < S; ++s)
            sum += Lpart[(((size_t)(s * 4 + b)) << 12) + n0 + t];
        invl[t] = 1.f / sum;
    }
    __syncthreads();

    {   // merge: thread (d = t>>2, 8 n at (t&3)*8); 16B fp16 loads
        const int d  = t >> 2;
        const int nb = (t & 3) * 8;
        float o[8] = {0.f, 0.f, 0.f, 0.f, 0.f, 0.f, 0.f, 0.f};
        for (int s = 0; s < S; ++s) {
            h16x8 v = *(const h16x8*)(
                Opart + (((size_t)((s * 4 + b) * 64 + d)) << 12) + n0 + nb);
#pragma unroll
            for (int j = 0; j < 8; ++j) o[j] += (float)v[j];
        }
#pragma unroll
        for (int j = 0; j < 8; ++j)
            attm[d * 33 + nb + j] = o[j] * invl[nb + j];
    }
    __syncthreads();

    const int nn = t & 31;
    const int e0 = (t >> 5) * 8;
    float acc[8];
#pragma unroll
    for (int i = 0; i < 8; ++i) acc[i] = bo[e0 + i];
#pragma unroll 8
    for (int d = 0; d < 64; ++d) {
        const float xv = attm[d * 33 + nn];
#pragma unroll
        for (int i = 0; i < 8; ++i) acc[i] += wo[(e0 + i) * 64 + d] * xv;
    }
#pragma unroll
    for (int i = 0; i < 8; ++i)
        out[((size_t)(b * 64 + e0 + i) << 12) + n0 + nn] = acc[i];
}

// ---------------------------------------------------------------------------
extern "C" void kernel_launch(void* const* d_in, const int* in_sizes, int n_in,
                              void* d_out, int out_size, void* d_ws, size_t ws_size,
                              hipStream_t stream) {
    const float* x   = (const float*)d_in[0];
    const float* gnw = (const float*)d_in[1];
    const float* gnb = (const float*)d_in[2];
    const float* wq  = (const float*)d_in[3];
    const float* bq  = (const float*)d_in[4];
    const float* wk  = (const float*)d_in[5];
    const float* bk  = (const float*)d_in[6];
    const float* wv  = (const float*)d_in[7];
    const float* bv  = (const float*)d_in[8];
    const float* wo  = (const float*)d_in[9];
    const float* bo  = (const float*)d_in[10];
    float* out = (float*)d_out;

    char* wsb = (char*)d_ws;
    float*          stats = (float*)wsb;                                  //   2 KB
    unsigned short* Qt    = (unsigned short*)(wsb + 2048);                //   2 MB
    unsigned short* Kf    = (unsigned short*)(wsb + 2048 + 2097152);      //   2 MB
    unsigned short* Vf    = (unsigned short*)(wsb + 2048 + 2 * 2097152);  //   2 MB

    const size_t base = 2048 + 3ull * 2097152;
    // per m-split slot: Lpart 4*4096*4 = 64 KB, Opart fp16 4*64*4096*2 = 2 MB
    auto need = [&](int S) {
        return base + (size_t)S * (65536 + 2097152);
    };
    // S=2: 4 MB partial round-trip, 2-way merge; attn grid 256 = 1 block/CU.
    const int S = (ws_size >= need(2)) ? 2 : 1;
    const int mspan = N_ / S;   // 2048 at S=2 -> NT = 16 tiles of 128 m
    float*    Lpart = (float*)(wsb + base);
    _Float16* Opart = (_Float16*)(wsb + base + (size_t)S * 65536);

    gn_stats_kernel<<<dim3(B_ * C_), dim3(1024), 0, stream>>>(x, stats);
    gn_qkv_kernel<<<dim3(B_ * 64), dim3(512), 0, stream>>>(
        x, stats, gnw, gnb, wq, bq, wk, bk, wv, bv, Qt, Kf, Vf);
    attn_kernel<<<dim3(128 * S), dim3(256), 0, stream>>>(
        Qt, Kf, Vf, Opart, Lpart, mspan);
    out_proj_kernel<<<dim3(B_ * 128), dim3(256), 0, stream>>>(
        Opart, Lpart, wo, bo, out, S);
}